// Round 9
// baseline (1338.158 us; speedup 1.0000x reference)
//
#include <hip/hip_runtime.h>
#include <hip/hip_bf16.h>
#include <stdint.h>

#define NN 8192
#define LDA 8320           // padded bf16 A row stride: 16640 B = 130*128B, channel-rotating
#define LDU 8320           // padded UT row stride (bf16)
#define DIM 256
#define NSPEC 32
#define ETA 0.5f
#define COEFF 0.125f       // D/(N*EPS^2) = 256/(8192*0.25)
#define LNEPS 1e-5f
#define KSTEPS (NN / 32)   // 256 MFMA K-steps per hop

typedef __attribute__((ext_vector_type(8))) short bf16x8;
typedef __attribute__((ext_vector_type(4))) float f32x4;
typedef __attribute__((ext_vector_type(4))) unsigned short u16x4;

__device__ __forceinline__ unsigned short bf2u(__hip_bfloat16 b) {
    union { __hip_bfloat16 b; unsigned short u; } c; c.b = b; return c.u;
}

// ---------------- cast A: f32 (8192x8192) -> bf16 Ab[m][LDA] row-major (NO transpose) --------
// Fully coalesced both sides: 1 KB contiguous per wave-instruction.
__global__ void cast_A(const float* __restrict__ A, __hip_bfloat16* __restrict__ Ab) {
    const long row = blockIdx.x;
    const float* src = A + row * NN;
    __hip_bfloat16* dst = Ab + row * LDA;
    const int t = threadIdx.x;
#pragma unroll
    for (int i = 0; i < 4; ++i) {
        int base = (i * 256 + t) * 8;
        float4 v0 = *(const float4*)(src + base);
        float4 v1 = *(const float4*)(src + base + 4);
        unsigned short pk[8];
        pk[0] = bf2u(__float2bfloat16(v0.x)); pk[1] = bf2u(__float2bfloat16(v0.y));
        pk[2] = bf2u(__float2bfloat16(v0.z)); pk[3] = bf2u(__float2bfloat16(v0.w));
        pk[4] = bf2u(__float2bfloat16(v1.x)); pk[5] = bf2u(__float2bfloat16(v1.y));
        pk[6] = bf2u(__float2bfloat16(v1.z)); pk[7] = bf2u(__float2bfloat16(v1.w));
        *(bf16x8*)(dst + base) = *(bf16x8*)pk;
    }
}

// ---------------- transpose+cast H: f32 (8192x256) -> bf16 UT0 (256 x LDU) ------------------
__global__ void transH(const float* __restrict__ H, __hip_bfloat16* __restrict__ UT0) {
    __shared__ float lds[64 * 260];
    const int t = threadIdx.x;
    const int n0 = blockIdx.x * 64;
#pragma unroll
    for (int i = 0; i < 16; ++i) {
        int idx = i * 256 + t;              // 4096 float4s = 64 n-rows x 64 groups
        int n = idx >> 6, c = idx & 63;
        float4 v = *(const float4*)&H[(long)(n0 + n) * DIM + c * 4];
        lds[n * 260 + c * 4 + 0] = v.x; lds[n * 260 + c * 4 + 1] = v.y;
        lds[n * 260 + c * 4 + 2] = v.z; lds[n * 260 + c * 4 + 3] = v.w;
    }
    __syncthreads();
#pragma unroll
    for (int j = 0; j < 8; ++j) {
        int idx = j * 256 + t;              // 2048 bf16x8 = 256 d-rows x 8 groups of 8 n
        int d = idx >> 3, g = idx & 7;
        unsigned short pk[8];
#pragma unroll
        for (int e = 0; e < 8; ++e)
            pk[e] = bf2u(__float2bfloat16(lds[(g * 8 + e) * 260 + d]));
        *(bf16x8*)&UT0[(long)d * LDU + n0 + g * 8] = *(bf16x8*)pk;
    }
}

// ---------------- hop: OUT[m,d] = sum_n Ab[m,n] * UTin[d,n]; writes UTout bf16 + Uf f32 -----
// A row-major (contig n = MFMA K), UT d-major (contig n = MFMA K) -> no transposes in the loop.
// Grid 256 blocks x 512 thr (8 waves = 2m x 4d); BM=32, BN=256 (full D -> A read exactly once).
// Barrier-free register pipeline, depth-4 prefetch: 20 loads in flight/wave covers HBM latency.
__launch_bounds__(512, 2)
__global__ void hop(const __hip_bfloat16* __restrict__ Ab,
                    const __hip_bfloat16* __restrict__ UTin,
                    __hip_bfloat16* __restrict__ UTout,
                    float* __restrict__ Ufout) {
    const int t = threadIdx.x;
    const int wv = t >> 6, l = t & 63;
    const int wm = wv & 1;             // m-half of BM=32
    const int wd = (wv >> 1) * 64;     // d-quarter base
    const int lr = l & 15;
    const int lk = (l >> 4) * 8;
    const long m0 = (long)blockIdx.x * 32 + wm * 16;

    const __hip_bfloat16* Ap = Ab + (m0 + lr) * (long)LDA + lk;
    const __hip_bfloat16* Bp = UTin + (long)(wd + lr) * LDU + lk;

    f32x4 acc[4];
#pragma unroll
    for (int dt = 0; dt < 4; ++dt) acc[dt] = (f32x4){0.f, 0.f, 0.f, 0.f};

    bf16x8 af[4];
    bf16x8 bfr[4][4];
#pragma unroll
    for (int p = 0; p < 4; ++p) {
        af[p] = *(const bf16x8*)(Ap + p * 32);
#pragma unroll
        for (int dt = 0; dt < 4; ++dt)
            bfr[p][dt] = *(const bf16x8*)(Bp + (long)dt * 16 * LDU + p * 32);
    }

#pragma unroll 4
    for (int kk = 0; kk < KSTEPS; ++kk) {
        const int cur = kk & 3;
#pragma unroll
        for (int dt = 0; dt < 4; ++dt)
            acc[dt] = __builtin_amdgcn_mfma_f32_16x16x32_bf16(af[cur], bfr[cur][dt],
                                                              acc[dt], 0, 0, 0);
        if (kk + 4 < KSTEPS) {
            af[cur] = *(const bf16x8*)(Ap + (kk + 4) * 32);
#pragma unroll
            for (int dt = 0; dt < 4; ++dt)
                bfr[cur][dt] = *(const bf16x8*)(Bp + (long)dt * 16 * LDU + (kk + 4) * 32);
        }
    }

    // C/D layout: col = lane&15 -> d within tile; row = (lane>>4)*4 + reg -> m
#pragma unroll
    for (int dt = 0; dt < 4; ++dt) {
        const int d = wd + dt * 16 + lr;
#pragma unroll
        for (int r = 0; r < 4; ++r) {
            const long m = m0 + (l >> 4) * 4 + r;
            UTout[(long)d * LDU + m] = __float2bfloat16(acc[dt][r]);
            Ufout[m * (long)DIM + d] = acc[dt][r];
        }
    }
}

// ---------------- Phi[k,s,d] = sum_n V[n,s] * Uk[n,d]  (f32, atomic split over n) ------------
__global__ void phi_kernel(const float* __restrict__ V, const float* __restrict__ H0,
                           const float* __restrict__ U1, const float* __restrict__ U2,
                           const float* __restrict__ U3, float* __restrict__ Phi) {
    __shared__ float ldsW[64 * NSPEC];   // 8 KB (V chunk)
    int t = threadIdx.x;
    int s0 = (t >> 6) * 8;
    int d0 = (t & 63) * 4;
    int n0 = blockIdx.x * 128;
    int k = blockIdx.y;
    const float* Hk = (k == 0) ? H0 : (k == 1) ? U1 : (k == 2) ? U2 : U3;
    float4 acc[8];
#pragma unroll
    for (int j = 0; j < 8; ++j) acc[j] = (float4){0.f, 0.f, 0.f, 0.f};

    for (int tile = 0; tile < 2; ++tile) {
        int nb = n0 + tile * 64;
#pragma unroll
        for (int i = 0; i < 8; ++i) {
            int idx = i * 256 + t;
            ldsW[idx] = V[(long)(nb + (idx >> 5)) * NSPEC + (idx & 31)];
        }
        __syncthreads();
        for (int nn = 0; nn < 64; ++nn) {
            float4 x = *(const float4*)&Hk[(long)(nb + nn) * DIM + d0];
#pragma unroll
            for (int j = 0; j < 8; ++j) {
                float vs = ldsW[nn * NSPEC + s0 + j];
                acc[j].x += vs * x.x; acc[j].y += vs * x.y;
                acc[j].z += vs * x.z; acc[j].w += vs * x.w;
            }
        }
        __syncthreads();
    }
#pragma unroll
    for (int j = 0; j < 8; ++j) {
        float* ph = &Phi[((k * NSPEC) + s0 + j) * DIM + d0];
        atomicAdd(ph + 0, acc[j].x);
        atomicAdd(ph + 1, acc[j].y);
        atomicAdd(ph + 2, acc[j].z);
        atomicAdd(ph + 3, acc[j].w);
    }
}

// ---------------- Tc[s,d] = spec_w*sum_k hw*q - lap*eig*sum_k hw*phi; + tail outputs ---------
__global__ void tc_kernel(const float* __restrict__ Phi,
                          const float* __restrict__ eigvals,
                          const float* __restrict__ spec_logits,
                          const float* __restrict__ lap_logits,
                          const float* __restrict__ hop_weights,
                          float* __restrict__ Tc,
                          float* __restrict__ out_tail) {
    int s = blockIdx.x, t = threadIdx.x;
    float hw0 = hop_weights[0], hw1 = hop_weights[1], hw2 = hop_weights[2], hw3 = hop_weights[3];
    float hm = fmaxf(fmaxf(hw0, hw1), fmaxf(hw2, hw3));
    hw0 = expf(hw0 - hm); hw1 = expf(hw1 - hm); hw2 = expf(hw2 - hm); hw3 = expf(hw3 - hm);
    float hs = hw0 + hw1 + hw2 + hw3;
    hw0 /= hs; hw1 /= hs; hw2 /= hs; hw3 /= hs;
    float hw[4] = {hw0, hw1, hw2, hw3};
    float sm = -1e30f;
    for (int j = 0; j < NSPEC; ++j) sm = fmaxf(sm, spec_logits[j]);
    float ssum = 0.f;
    for (int j = 0; j < NSPEC; ++j) ssum += expf(spec_logits[j] - sm);
    float spec_w_s = expf(spec_logits[s] - sm) / ssum;
    float lp = lap_logits[s];
    float lap = (lp > 20.f) ? lp : log1pf(expf(lp));
    float le = lap * eigvals[s];

    __shared__ float red[4];
    float accR = 0.f, accL = 0.f;
    for (int k = 0; k < 4; ++k) {
        float phi = Phi[(k * NSPEC + s) * DIM + t];
        float v = phi * phi;
        for (int off = 32; off; off >>= 1) v += __shfl_xor(v, off);
        if ((t & 63) == 0) red[t >> 6] = v;
        __syncthreads();
        float ssq = red[0] + red[1] + red[2] + red[3];
        __syncthreads();
        float q = COEFF * phi / (1.f + COEFF * ssq);   // Sherman-Morrison: solve(I+c*pp^T, p)
        accR += hw[k] * q;
        accL += hw[k] * phi;
    }
    Tc[s * DIM + t] = spec_w_s * accR - le * accL;
    if (s == 0) {
        if (t < 4) out_tail[t] = hw[t];
        if (t < NSPEC) out_tail[4 + t] = expf(spec_logits[t] - sm) / ssum;
    }
}

// ---------------- final: G=V@Tc, H_half=H+ETA*G, soft-threshold, LayerNorm ----------------
__launch_bounds__(256)
__global__ void final_kernel(const float* __restrict__ H, const float* __restrict__ V,
                             const float* __restrict__ Tc, const float* __restrict__ thr,
                             const float* __restrict__ gamma, const float* __restrict__ beta,
                             float* __restrict__ out) {
    __shared__ float tc[NSPEC * DIM];   // 32 KB
    int t = threadIdx.x;
    {
        const float4* s4 = (const float4*)Tc;
        float4* d4 = (float4*)tc;
        for (int i = 0; i < 8; ++i) d4[i * 256 + t] = s4[i * 256 + t];
    }
    __syncthreads();
    int w = t >> 6, l = t & 63;
    long row = (long)blockIdx.x * 4 + w;
    int d0 = l * 4;
    const float* vrow = V + row * NSPEC;
    float4 G = {0.f, 0.f, 0.f, 0.f};
#pragma unroll 8
    for (int s = 0; s < NSPEC; ++s) {
        float vs = vrow[s];
        float4 c4 = *(const float4*)&tc[s * DIM + d0];
        G.x += vs * c4.x; G.y += vs * c4.y; G.z += vs * c4.z; G.w += vs * c4.w;
    }
    float4 h = *(const float4*)&H[row * DIM + d0];
    float4 th = *(const float4*)&thr[d0];
    float y[4];
    y[0] = h.x + ETA * G.x; y[1] = h.y + ETA * G.y;
    y[2] = h.z + ETA * G.z; y[3] = h.w + ETA * G.w;
    float tv[4] = {th.x, th.y, th.z, th.w};
    float s1 = 0.f, s2 = 0.f;
#pragma unroll
    for (int j = 0; j < 4; ++j) {
        float a = fabsf(y[j]) - tv[j];
        y[j] = (a > 0.f) ? copysignf(a, y[j]) : 0.f;
        s1 += y[j];
        s2 += y[j] * y[j];
    }
    for (int off = 32; off; off >>= 1) { s1 += __shfl_xor(s1, off); s2 += __shfl_xor(s2, off); }
    float mean = s1 * (1.f / DIM);
    float var = s2 * (1.f / DIM) - mean * mean;
    float inv = rsqrtf(var + LNEPS);
    float4 g4 = *(const float4*)&gamma[d0];
    float4 b4 = *(const float4*)&beta[d0];
    float4 o;
    o.x = (y[0] - mean) * inv * g4.x + b4.x;
    o.y = (y[1] - mean) * inv * g4.y + b4.y;
    o.z = (y[2] - mean) * inv * g4.z + b4.z;
    o.w = (y[3] - mean) * inv * g4.w + b4.w;
    *(float4*)&out[row * DIM + d0] = o;
}

extern "C" void kernel_launch(void* const* d_in, const int* in_sizes, int n_in,
                              void* d_out, int out_size, void* d_ws, size_t ws_size,
                              hipStream_t stream) {
    const float* H = (const float*)d_in[0];
    const float* A = (const float*)d_in[1];
    const float* V = (const float*)d_in[2];
    const float* eigvals = (const float*)d_in[3];
    const float* spec_logits = (const float*)d_in[4];
    const float* lap_logits = (const float*)d_in[5];
    const float* hop_weights = (const float*)d_in[6];
    const float* threshold = (const float*)d_in[7];
    const float* ln_gamma = (const float*)d_in[8];
    const float* ln_beta = (const float*)d_in[9];

    char* ws = (char*)d_ws;
    __hip_bfloat16* Ab  = (__hip_bfloat16*)ws;                       // 8192*8320*2 = 136,314,880
    __hip_bfloat16* UT0 = (__hip_bfloat16*)(ws + 136314880);         // 256*8320*2 = 4,259,840
    __hip_bfloat16* UT1 = (__hip_bfloat16*)(ws + 140574720);
    __hip_bfloat16* UT2 = (__hip_bfloat16*)(ws + 144834560);
    __hip_bfloat16* UT3 = (__hip_bfloat16*)(ws + 149094400);
    float* Uf1 = (float*)(ws + 153354240);                           // 8192*256*4 = 8,388,608
    float* Uf2 = (float*)(ws + 161742848);
    float* Uf3 = (float*)(ws + 170131456);
    float* Phi = (float*)(ws + 178520064);                           // 128 KB
    float* Tc  = (float*)(ws + 178651136);                           // 32 KB
    float* out = (float*)d_out;

    hipMemsetAsync(Phi, 0, 4 * NSPEC * DIM * sizeof(float), stream);

    cast_A<<<8192, 256, 0, stream>>>(A, Ab);
    transH<<<128, 256, 0, stream>>>(H, UT0);

    hop<<<256, 512, 0, stream>>>(Ab, UT0, UT1, Uf1);
    hop<<<256, 512, 0, stream>>>(Ab, UT1, UT2, Uf2);
    hop<<<256, 512, 0, stream>>>(Ab, UT2, UT3, Uf3);

    phi_kernel<<<dim3(64, 4), 256, 0, stream>>>(V, H, Uf1, Uf2, Uf3, Phi);
    tc_kernel<<<NSPEC, 256, 0, stream>>>(Phi, eigvals, spec_logits, lap_logits, hop_weights,
                                         Tc, out + (long)NN * DIM);
    final_kernel<<<2048, 256, 0, stream>>>(H, V, Tc, threshold, ln_gamma, ln_beta, out);
}